// Round 15
// baseline (264.107 us; speedup 1.0000x reference)
//
#include <hip/hip_runtime.h>
#include <hip/hip_fp16.h>

// GraphEncoder: 3x GraphConv(norm='both'), DIM=64, fixed graph.
// R15: prep execution fixes, layers untouched (R14: 8 nodes/wave, 16B/lane).
//  - edge_hist: 256 blocks x 1 chunk (was 128x2) -> 2x CU coverage of the
//    LDS-atomic-bound histogram; partial 16MB (aliased by bpack after use).
//  - part_scan fused into prescale kernel: block 0 scans while blocks 1..255
//    reduce rs_out + prescale -> whole-GPU-idle 1-block dispatch eliminated.
//  7 dispatches. fp16 inter-layer tables, fp32 math.

#define N_NODES 65536
#define N_EDGES 1048576
#define DIM 64

#define CHUNKS 256
#define EPC (N_EDGES / CHUNKS)        // 4096 edges per chunk
#define OH_WORDS 16384                // 65536 nodes packed 4-per-word (64KB)

struct alignas(8) h4 { __half2 a, b; };   // 4 halves = 8 B

// --- one pass over edges: dst partition hist + packed src hist + zero rows ---
__global__ void edge_hist(const int* __restrict__ src, const int* __restrict__ dst,
                          int* __restrict__ block_hist, unsigned* __restrict__ partial,
                          uint2* __restrict__ zeroA, uint2* __restrict__ zeroB) {
    __shared__ unsigned h[OH_WORDS];  // 64 KB: src histogram, 8-bit x4 packed
    __shared__ int bh[256];
    int t = threadIdx.x;
    int j = blockIdx.x;               // 0..255, one chunk each
    for (int i = t; i < OH_WORDS; i += 256) h[i] = 0;
    bh[t] = 0;
    __syncthreads();
    if (j == 0) {                     // zero row (row N_NODES, 128 B each table)
        if (t < 16) zeroA[t] = make_uint2(0u, 0u);
        else if (t < 32) zeroB[t - 16] = make_uint2(0u, 0u);
    }
    int base = j * EPC;
    for (int i = t; i < EPC; i += 256) {
        int s = src[base + i];
        int d = dst[base + i];
        atomicAdd(&h[s >> 2], 1u << ((s & 3) * 8));   // per-chunk count << 255
        atomicAdd(&bh[d >> 8], 1);
    }
    __syncthreads();
    unsigned* dp = partial + (size_t)j * OH_WORDS;
    for (int i = t; i < OH_WORDS; i += 256) dp[i] = h[i];
    block_hist[t * CHUNKS + j] = bh[t];               // [bucket][chunk]
}

// --- block 0: exclusive scan of 65536 (bucket-major); all: rs_out + prescale ---
__global__ void prescale_scan(const int* __restrict__ bhist, int* __restrict__ so,
                              const unsigned* __restrict__ partial,
                              float* __restrict__ rs_out,
                              const float4* __restrict__ x4, h4* __restrict__ xs) {
    __shared__ float rsl[256];
    __shared__ int sscan[256];
    int b = blockIdx.x;
    int t = threadIdx.x;

    if (b == 0) {
        // thread t owns bucket t: 256 chunk values
        const int4* b4 = (const int4*)(bhist + t * CHUNKS);
        int4 v[64];
        int sum = 0;
        #pragma unroll 8
        for (int i = 0; i < 64; i++) {
            v[i] = b4[i];
            sum += v[i].x + v[i].y + v[i].z + v[i].w;
        }
        sscan[t] = sum;
        __syncthreads();
        for (int off = 1; off < 256; off <<= 1) {
            int u2 = (t >= off) ? sscan[t - off] : 0;
            __syncthreads();
            sscan[t] += u2;
            __syncthreads();
        }
        int run = sscan[t] - sum;                     // exclusive bucket base
        int* o = so + t * CHUNKS;
        #pragma unroll 8
        for (int i = 0; i < 64; i++) {
            o[4 * i + 0] = run; run += v[i].x;
            o[4 * i + 1] = run; run += v[i].y;
            o[4 * i + 2] = run; run += v[i].z;
            o[4 * i + 3] = run; run += v[i].w;
        }
        __syncthreads();                              // re-align for prescale part
    }

    if (t < 64) {
        int w = b * 64 + t;                           // word = 4 nodes
        int c0 = 0, c1 = 0, c2 = 0, c3 = 0;
        for (int c = 0; c < CHUNKS; c++) {
            unsigned v = partial[(size_t)c * OH_WORDS + w];
            c0 += (int)(v & 255u);
            c1 += (int)((v >> 8) & 255u);
            c2 += (int)((v >> 16) & 255u);
            c3 += (int)(v >> 24);
        }
        float4 r = make_float4(rsqrtf(c0 < 1 ? 1.0f : (float)c0),
                               rsqrtf(c1 < 1 ? 1.0f : (float)c1),
                               rsqrtf(c2 < 1 ? 1.0f : (float)c2),
                               rsqrtf(c3 < 1 ? 1.0f : (float)c3));
        ((float4*)rs_out)[w] = r;
        rsl[t * 4 + 0] = r.x; rsl[t * 4 + 1] = r.y;
        rsl[t * 4 + 2] = r.z; rsl[t * 4 + 3] = r.w;
    }
    __syncthreads();
    int rowbase = b * 4096;                           // 256 nodes x 16 float4
    for (int i = t; i < 4096; i += 256) {
        float r = rsl[i >> 4];
        float4 v = x4[rowbase + i];
        h4 o;
        o.a = __float22half2_rn(make_float2(v.x * r, v.y * r));
        o.b = __float22half2_rn(make_float2(v.z * r, v.w * r));
        xs[rowbase + i] = o;
    }
}

// --- scatter packed (src | dlow<<16) into bucket order, 256 chunks ---
__global__ void part_scatter(const int* __restrict__ src, const int* __restrict__ dst,
                             const int* __restrict__ so, int* __restrict__ bpack) {
    __shared__ int cur[256];
    cur[threadIdx.x] = so[threadIdx.x * CHUNKS + blockIdx.x];
    __syncthreads();
    int base = blockIdx.x * EPC;
    for (int i = threadIdx.x; i < EPC; i += 256) {
        int s = src[base + i];
        int d = dst[base + i];
        int pos = atomicAdd(&cur[d >> 8], 1);         // LDS atomic (rank)
        bpack[pos] = s | ((d & 255) << 16);
    }
}

// --- per-bucket (LDS-staged): hist -> scan -> row_start+rs_in -> csr emit ---
__global__ void bucket_fused(const int* __restrict__ bpack, const int* __restrict__ so,
                             int* __restrict__ row_start, float* __restrict__ rs_in,
                             unsigned short* __restrict__ csr_src) {
    __shared__ int stage[8192];                       // 32 KB
    __shared__ int h[256], sc[256], cur[256];
    int b = blockIdx.x;
    int t = threadIdx.x;
    int beg = so[b * CHUNKS];
    int end = (b == 255) ? N_EDGES : so[(b + 1) * CHUNKS];
    int n = end - beg;
    h[t] = 0;
    __syncthreads();
    for (int i = t; i < n; i += 256) {
        int p = bpack[beg + i];
        if (i < 8192) stage[i] = p;
        atomicAdd(&h[(p >> 16) & 255], 1);
    }
    __syncthreads();
    int d = h[t];
    sc[t] = d;
    __syncthreads();
    for (int off = 1; off < 256; off <<= 1) {
        int v = (t >= off) ? sc[t - off] : 0;
        __syncthreads();
        sc[t] += v;
        __syncthreads();
    }
    int rsv = beg + sc[t] - d;
    int node = b * 256 + t;
    row_start[node] = rsv;
    rs_in[node] = rsqrtf(d < 1 ? 1.0f : (float)d);
    if (node == N_NODES - 1) row_start[N_NODES] = N_EDGES;
    cur[t] = rsv;
    __syncthreads();
    for (int i = t; i < n; i += 256) {
        int p = (i < 8192) ? stage[i] : bpack[beg + i];
        int pos = atomicAdd(&cur[(p >> 16) & 255], 1);
        csr_src[pos] = (unsigned short)(p & 0xFFFF);
    }
}

// --- fused layer (R14-proven): 8 nodes/wave, 8 lanes/node, 16B/lane gather ---
template<bool SCALE_OUT>
__global__ void fused_layer(const uint4* __restrict__ xs16, const int* __restrict__ row_start,
                            const unsigned short* __restrict__ csr,
                            const float* __restrict__ rs_out, const float* __restrict__ rs_in,
                            const float* __restrict__ W, const float* __restrict__ b,
                            void* __restrict__ outp) {
    __shared__ float4 Ws4[DIM * 16];   // [row][col/4]
    __shared__ float4 bs4[16];
    {
        const float4* Wg = (const float4*)W;
        for (int i = threadIdx.x; i < DIM * 16; i += blockDim.x) Ws4[i] = Wg[i];
        if (threadIdx.x < 16) bs4[threadIdx.x] = ((const float4*)b)[threadIdx.x];
    }
    __syncthreads();

    int wave_id = threadIdx.x >> 6;
    int lane = threadIdx.x & 63;
    int g = lane >> 3;                 // 8 groups (nodes) per wave
    int l = lane & 7;                  // lane holds dims 8l..8l+7
    int node = blockIdx.x * 32 + wave_id * 8 + g;

    int beg = row_start[node];
    int end = row_start[node + 1];

    float a0 = 0.f, a1 = 0.f, a2 = 0.f, a3 = 0.f,
          a4 = 0.f, a5 = 0.f, a6 = 0.f, a7 = 0.f;
    for (int k = beg; k < end; k += 8) {
        int s[8];
        #pragma unroll
        for (int j = 0; j < 8; j++) {
            int kk = k + j;
            int idx = csr[kk];                         // csr padded by 16 -> safe
            s[j] = (kk < end) ? idx : N_NODES;         // OOB -> zero row (L1-hot)
        }
        uint4 v[8];
        #pragma unroll
        for (int j = 0; j < 8; j++) v[j] = xs16[s[j] * 8 + l];   // 16B/lane
        #pragma unroll
        for (int j = 0; j < 8; j++) {
            float2 f0 = __half22float2(*(const __half2*)&v[j].x);
            float2 f1 = __half22float2(*(const __half2*)&v[j].y);
            float2 f2 = __half22float2(*(const __half2*)&v[j].z);
            float2 f3 = __half22float2(*(const __half2*)&v[j].w);
            a0 += f0.x; a1 += f0.y; a2 += f1.x; a3 += f1.y;
            a4 += f2.x; a5 += f2.y; a6 += f3.x; a7 += f3.y;
        }
    }
    float ri = rs_in[node];
    a0 *= ri; a1 *= ri; a2 *= ri; a3 *= ri;
    a4 *= ri; a5 *= ri; a6 *= ri; a7 *= ri;

    float4 o0 = bs4[2 * l];
    float4 o1 = bs4[2 * l + 1];
    int gbase = g << 3;
    #pragma unroll
    for (int m = 0; m < 8; m++) {
        float q0 = __shfl(a0, gbase + m, 64);
        float q1 = __shfl(a1, gbase + m, 64);
        float q2 = __shfl(a2, gbase + m, 64);
        float q3 = __shfl(a3, gbase + m, 64);
        float q4 = __shfl(a4, gbase + m, 64);
        float q5 = __shfl(a5, gbase + m, 64);
        float q6 = __shfl(a6, gbase + m, 64);
        float q7 = __shfl(a7, gbase + m, 64);
        int rb = (8 * m) * 16 + 2 * l;
        float4 w;
        w = Ws4[rb];            o0.x += q0*w.x; o0.y += q0*w.y; o0.z += q0*w.z; o0.w += q0*w.w;
        w = Ws4[rb + 1];        o1.x += q0*w.x; o1.y += q0*w.y; o1.z += q0*w.z; o1.w += q0*w.w;
        w = Ws4[rb + 16];       o0.x += q1*w.x; o0.y += q1*w.y; o0.z += q1*w.z; o0.w += q1*w.w;
        w = Ws4[rb + 17];       o1.x += q1*w.x; o1.y += q1*w.y; o1.z += q1*w.z; o1.w += q1*w.w;
        w = Ws4[rb + 32];       o0.x += q2*w.x; o0.y += q2*w.y; o0.z += q2*w.z; o0.w += q2*w.w;
        w = Ws4[rb + 33];       o1.x += q2*w.x; o1.y += q2*w.y; o1.z += q2*w.z; o1.w += q2*w.w;
        w = Ws4[rb + 48];       o0.x += q3*w.x; o0.y += q3*w.y; o0.z += q3*w.z; o0.w += q3*w.w;
        w = Ws4[rb + 49];       o1.x += q3*w.x; o1.y += q3*w.y; o1.z += q3*w.z; o1.w += q3*w.w;
        w = Ws4[rb + 64];       o0.x += q4*w.x; o0.y += q4*w.y; o0.z += q4*w.z; o0.w += q4*w.w;
        w = Ws4[rb + 65];       o1.x += q4*w.x; o1.y += q4*w.y; o1.z += q4*w.z; o1.w += q4*w.w;
        w = Ws4[rb + 80];       o0.x += q5*w.x; o0.y += q5*w.y; o0.z += q5*w.z; o0.w += q5*w.w;
        w = Ws4[rb + 81];       o1.x += q5*w.x; o1.y += q5*w.y; o1.z += q5*w.z; o1.w += q5*w.w;
        w = Ws4[rb + 96];       o0.x += q6*w.x; o0.y += q6*w.y; o0.z += q6*w.z; o0.w += q6*w.w;
        w = Ws4[rb + 97];       o1.x += q6*w.x; o1.y += q6*w.y; o1.z += q6*w.z; o1.w += q6*w.w;
        w = Ws4[rb + 112];      o0.x += q7*w.x; o0.y += q7*w.y; o0.z += q7*w.z; o0.w += q7*w.w;
        w = Ws4[rb + 113];      o1.x += q7*w.x; o1.y += q7*w.y; o1.z += q7*w.z; o1.w += q7*w.w;
    }
    if (SCALE_OUT) {
        float ro = rs_out[node];
        o0.x = (o0.x < 0.f ? 0.f : o0.x) * ro;
        o0.y = (o0.y < 0.f ? 0.f : o0.y) * ro;
        o0.z = (o0.z < 0.f ? 0.f : o0.z) * ro;
        o0.w = (o0.w < 0.f ? 0.f : o0.w) * ro;
        o1.x = (o1.x < 0.f ? 0.f : o1.x) * ro;
        o1.y = (o1.y < 0.f ? 0.f : o1.y) * ro;
        o1.z = (o1.z < 0.f ? 0.f : o1.z) * ro;
        o1.w = (o1.w < 0.f ? 0.f : o1.w) * ro;
        uint4 ho;
        *(__half2*)&ho.x = __float22half2_rn(make_float2(o0.x, o0.y));
        *(__half2*)&ho.y = __float22half2_rn(make_float2(o0.z, o0.w));
        *(__half2*)&ho.z = __float22half2_rn(make_float2(o1.x, o1.y));
        *(__half2*)&ho.w = __float22half2_rn(make_float2(o1.z, o1.w));
        ((uint4*)outp)[node * 8 + l] = ho;             // fp16 next-layer table
    } else {
        float4* o4 = (float4*)outp;
        o4[node * 16 + 2 * l]     = o0;                // fp32 final output
        o4[node * 16 + 2 * l + 1] = o1;
    }
}

extern "C" void kernel_launch(void* const* d_in, const int* in_sizes, int n_in,
                              void* d_out, int out_size, void* d_ws, size_t ws_size,
                              hipStream_t stream) {
    const float* x   = (const float*)d_in[0];
    const int*   ei  = (const int*)d_in[1];
    const int*   src = ei;
    const int*   dst = ei + N_EDGES;
    const float* W1 = (const float*)d_in[3];
    const float* b1 = (const float*)d_in[4];
    const float* W2 = (const float*)d_in[5];
    const float* b2 = (const float*)d_in[6];
    const float* W3 = (const float*)d_in[7];
    const float* b3 = (const float*)d_in[8];
    float* out = (float*)d_out;

    // workspace (~36 MB):
    // rs[2N] | row_start[N+256] | block_hist[64K] | so[64K] | csr[E+16] u16 |
    // bufA[(N+1)*128B] | bufB[(N+1)*128B] | partial[256*16K u32 = 16MB]
    // alias: bpack (4MB) over partial head (partial dead after prescale_scan).
    char* ws = (char*)d_ws;
    float* rs        = (float*)ws;                                 // [2N]
    float* rs_out    = rs;
    float* rs_in     = rs + N_NODES;
    int*   row_start = (int*)(rs + 2 * N_NODES);                   // [N+256]
    int*   block_h   = row_start + (N_NODES + 256);                // [65536]
    int*   so        = block_h + 256 * CHUNKS;                     // [65536]
    unsigned short* csr_src = (unsigned short*)(so + 256 * CHUNKS);// [E+16]
    h4*    bufA      = (h4*)(csr_src + N_EDGES + 16);              // [(N+1)*16]
    h4*    bufB      = bufA + (size_t)(N_NODES + 1) * 16;          // [(N+1)*16]
    unsigned* partial = (unsigned*)(bufB + (size_t)(N_NODES + 1) * 16); // 16 MB
    int*   bpack     = (int*)partial;                              // 4 MB alias
    uint2* zeroA     = (uint2*)(bufA + (size_t)N_NODES * 16);      // row N_NODES
    uint2* zeroB     = (uint2*)(bufB + (size_t)N_NODES * 16);

    const int fb = N_NODES / 32;      // 2048 blocks (8 nodes/wave x 4 waves)

    edge_hist    <<<CHUNKS, 256, 0, stream>>>(src, dst, block_h, partial, zeroA, zeroB);
    prescale_scan<<<CHUNKS, 256, 0, stream>>>(block_h, so, partial, rs_out,
                                              (const float4*)x, bufA);
    part_scatter <<<CHUNKS, 256, 0, stream>>>(src, dst, so, bpack);
    bucket_fused <<<CHUNKS, 256, 0, stream>>>(bpack, so, row_start, rs_in, csr_src);

    // layers: bufA -> bufB(fp16, scaled) -> bufA(fp16, scaled) -> d_out (fp32)
    fused_layer<true ><<<fb, 256, 0, stream>>>((const uint4*)bufA, row_start, csr_src, rs_out, rs_in, W1, b1, (void*)bufB);
    fused_layer<true ><<<fb, 256, 0, stream>>>((const uint4*)bufB, row_start, csr_src, rs_out, rs_in, W2, b2, (void*)bufA);
    fused_layer<false><<<fb, 256, 0, stream>>>((const uint4*)bufA, row_start, csr_src, rs_out, rs_in, W3, b3, (void*)out);
}

// Round 16
// 244.323 us; speedup vs baseline: 1.0810x; 1.0810x over previous
//
#include <hip/hip_runtime.h>
#include <hip/hip_fp16.h>

// GraphEncoder: 3x GraphConv(norm='both'), DIM=64, fixed graph.
// R16: exact R14 (best 248.5us) + ONE fix: oh2p_prescale reduce parallelized
// (R14: 64/256 lanes x 128 serial strided loads -> latency-bound, proven by
// R15's blow-up at 256 chunks). Now all 256 lanes: (word, chunk-quarter)
// layout, 32 chunks each, LDS 4->1 combine. R15's fused scan reverted
// (int4 v[64] scratch-spilled; 256-chunk partial doubled the reduce).

#define N_NODES 65536
#define N_EDGES 1048576
#define DIM 64

#define CHUNKS 256
#define EPC (N_EDGES / CHUNKS)        // 4096 edges per scatter chunk
#define HB 128                        // edge_hist blocks (2 chunks each)
#define OH_WORDS 16384                // 65536 nodes packed 4-per-word (64KB)

struct alignas(8) h4 { __half2 a, b; };   // 4 halves = 8 B

// --- one pass over edges: dst partition hist + packed src hist + zero rows ---
__global__ void edge_hist(const int* __restrict__ src, const int* __restrict__ dst,
                          int* __restrict__ block_hist, unsigned* __restrict__ partial,
                          uint2* __restrict__ zeroA, uint2* __restrict__ zeroB) {
    __shared__ unsigned h[OH_WORDS];  // 64 KB: src histogram, 8-bit x4 packed
    __shared__ int bh[2][256];
    int t = threadIdx.x;
    int j = blockIdx.x;               // 0..127
    for (int i = t; i < OH_WORDS; i += 256) h[i] = 0;
    bh[0][t] = 0; bh[1][t] = 0;
    __syncthreads();
    if (j == 0) {                     // zero row (row N_NODES, 128 B each table)
        if (t < 16) zeroA[t] = make_uint2(0u, 0u);
        else if (t < 32) zeroB[t - 16] = make_uint2(0u, 0u);
    }
    int base = j * (2 * EPC);
    for (int i = t; i < 2 * EPC; i += 256) {
        int s = src[base + i];
        int d = dst[base + i];
        atomicAdd(&h[s >> 2], 1u << ((s & 3) * 8));
        atomicAdd(&bh[i >> 12][d >> 8], 1);
    }
    __syncthreads();
    unsigned* dp = partial + (size_t)j * OH_WORDS;
    for (int i = t; i < OH_WORDS; i += 256) dp[i] = h[i];
    block_hist[t * CHUNKS + 2 * j]     = bh[0][t];
    block_hist[t * CHUNKS + 2 * j + 1] = bh[1][t];
}

// --- exclusive scan of 65536 (bucket-major [bucket][chunk]) ---
__global__ void part_scan(const int* __restrict__ bh, int* __restrict__ so) {
    __shared__ int s[1024];
    int t = threadIdx.x;
    const int4* b4 = (const int4*)(bh + t * 64);
    int4 v[16];
    int sum = 0;
    #pragma unroll
    for (int i = 0; i < 16; i++) {
        v[i] = b4[i];
        sum += v[i].x + v[i].y + v[i].z + v[i].w;
    }
    s[t] = sum;
    __syncthreads();
    for (int off = 1; off < 1024; off <<= 1) {
        int u = (t >= off) ? s[t - off] : 0;
        __syncthreads();
        s[t] += u;
        __syncthreads();
    }
    int run = s[t] - sum;
    int* o = so + t * 64;
    #pragma unroll
    for (int i = 0; i < 16; i++) {
        o[4 * i + 0] = run; run += v[i].x;
        o[4 * i + 1] = run; run += v[i].y;
        o[4 * i + 2] = run; run += v[i].z;
        o[4 * i + 3] = run; run += v[i].w;
    }
}

// --- scatter packed (src | dlow<<16) into bucket order, 256 chunks ---
__global__ void part_scatter(const int* __restrict__ src, const int* __restrict__ dst,
                             const int* __restrict__ so, int* __restrict__ bpack) {
    __shared__ int cur[256];
    cur[threadIdx.x] = so[threadIdx.x * CHUNKS + blockIdx.x];
    __syncthreads();
    int base = blockIdx.x * EPC;
    for (int i = threadIdx.x; i < EPC; i += 256) {
        int s = src[base + i];
        int d = dst[base + i];
        int pos = atomicAdd(&cur[d >> 8], 1);
        bpack[pos] = s | ((d & 255) << 16);
    }
}

// --- per-bucket (LDS-staged): hist -> scan -> row_start+rs_in -> csr emit ---
__global__ void bucket_fused(const int* __restrict__ bpack, const int* __restrict__ so,
                             int* __restrict__ row_start, float* __restrict__ rs_in,
                             unsigned short* __restrict__ csr_src) {
    __shared__ int stage[8192];                        // 32 KB
    __shared__ int h[256], sc[256], cur[256];
    int b = blockIdx.x;
    int t = threadIdx.x;
    int beg = so[b * CHUNKS];
    int end = (b == 255) ? N_EDGES : so[(b + 1) * CHUNKS];
    int n = end - beg;
    h[t] = 0;
    __syncthreads();
    for (int i = t; i < n; i += 256) {
        int p = bpack[beg + i];
        if (i < 8192) stage[i] = p;
        atomicAdd(&h[(p >> 16) & 255], 1);
    }
    __syncthreads();
    int d = h[t];
    sc[t] = d;
    __syncthreads();
    for (int off = 1; off < 256; off <<= 1) {
        int v = (t >= off) ? sc[t - off] : 0;
        __syncthreads();
        sc[t] += v;
        __syncthreads();
    }
    int rsv = beg + sc[t] - d;
    int node = b * 256 + t;
    row_start[node] = rsv;
    rs_in[node] = rsqrtf(d < 1 ? 1.0f : (float)d);
    if (node == N_NODES - 1) row_start[N_NODES] = N_EDGES;
    cur[t] = rsv;
    __syncthreads();
    for (int i = t; i < n; i += 256) {
        int p = (i < 8192) ? stage[i] : bpack[beg + i];
        int pos = atomicAdd(&cur[(p >> 16) & 255], 1);
        csr_src[pos] = (unsigned short)(p & 0xFFFF);
    }
}

// --- reduce src hists -> rs_out + fp16 prescale; ALL 256 lanes on the reduce ---
__global__ void oh2p_prescale(const unsigned* __restrict__ partial,
                              float* __restrict__ rs_out,
                              const float4* __restrict__ x4, h4* __restrict__ xs) {
    __shared__ int4 psum[256];        // [quarter][word] partial sums
    __shared__ float rsl[256];
    int b = blockIdx.x;
    int t = threadIdx.x;
    {
        int wl = t & 63;              // word-in-block 0..63
        int q  = t >> 6;              // chunk quarter 0..3
        int w = b * 64 + wl;
        int c0 = 0, c1 = 0, c2 = 0, c3 = 0;
        const unsigned* p = partial + (size_t)(q * (HB / 4)) * OH_WORDS + w;
        #pragma unroll 4
        for (int c = 0; c < HB / 4; c++) {
            unsigned v = p[(size_t)c * OH_WORDS];
            c0 += (int)(v & 255u);
            c1 += (int)((v >> 8) & 255u);
            c2 += (int)((v >> 16) & 255u);
            c3 += (int)(v >> 24);
        }
        psum[t] = make_int4(c0, c1, c2, c3);
    }
    __syncthreads();
    if (t < 64) {
        int4 a = psum[t], b2 = psum[t + 64], c = psum[t + 128], d = psum[t + 192];
        int c0 = a.x + b2.x + c.x + d.x;
        int c1 = a.y + b2.y + c.y + d.y;
        int c2 = a.z + b2.z + c.z + d.z;
        int c3 = a.w + b2.w + c.w + d.w;
        int w = b * 64 + t;
        float4 r = make_float4(rsqrtf(c0 < 1 ? 1.0f : (float)c0),
                               rsqrtf(c1 < 1 ? 1.0f : (float)c1),
                               rsqrtf(c2 < 1 ? 1.0f : (float)c2),
                               rsqrtf(c3 < 1 ? 1.0f : (float)c3));
        ((float4*)rs_out)[w] = r;
        rsl[t * 4 + 0] = r.x; rsl[t * 4 + 1] = r.y;
        rsl[t * 4 + 2] = r.z; rsl[t * 4 + 3] = r.w;
    }
    __syncthreads();
    int rowbase = b * 4096;           // 256 nodes x 16 float4
    for (int i = t; i < 4096; i += 256) {
        float r = rsl[i >> 4];
        float4 v = x4[rowbase + i];
        h4 o;
        o.a = __float22half2_rn(make_float2(v.x * r, v.y * r));
        o.b = __float22half2_rn(make_float2(v.z * r, v.w * r));
        xs[rowbase + i] = o;
    }
}

// --- fused layer (R14-proven): 8 nodes/wave, 8 lanes/node, 16B/lane gather ---
template<bool SCALE_OUT>
__global__ void fused_layer(const uint4* __restrict__ xs16, const int* __restrict__ row_start,
                            const unsigned short* __restrict__ csr,
                            const float* __restrict__ rs_out, const float* __restrict__ rs_in,
                            const float* __restrict__ W, const float* __restrict__ b,
                            void* __restrict__ outp) {
    __shared__ float4 Ws4[DIM * 16];   // [row][col/4]
    __shared__ float4 bs4[16];
    {
        const float4* Wg = (const float4*)W;
        for (int i = threadIdx.x; i < DIM * 16; i += blockDim.x) Ws4[i] = Wg[i];
        if (threadIdx.x < 16) bs4[threadIdx.x] = ((const float4*)b)[threadIdx.x];
    }
    __syncthreads();

    int wave_id = threadIdx.x >> 6;
    int lane = threadIdx.x & 63;
    int g = lane >> 3;                 // 8 groups (nodes) per wave
    int l = lane & 7;                  // lane holds dims 8l..8l+7
    int node = blockIdx.x * 32 + wave_id * 8 + g;

    int beg = row_start[node];
    int end = row_start[node + 1];

    float a0 = 0.f, a1 = 0.f, a2 = 0.f, a3 = 0.f,
          a4 = 0.f, a5 = 0.f, a6 = 0.f, a7 = 0.f;
    for (int k = beg; k < end; k += 8) {
        int s[8];
        #pragma unroll
        for (int j = 0; j < 8; j++) {
            int kk = k + j;
            int idx = csr[kk];                         // csr padded by 16 -> safe
            s[j] = (kk < end) ? idx : N_NODES;         // OOB -> zero row (L1-hot)
        }
        uint4 v[8];
        #pragma unroll
        for (int j = 0; j < 8; j++) v[j] = xs16[s[j] * 8 + l];   // 16B/lane
        #pragma unroll
        for (int j = 0; j < 8; j++) {
            float2 f0 = __half22float2(*(const __half2*)&v[j].x);
            float2 f1 = __half22float2(*(const __half2*)&v[j].y);
            float2 f2 = __half22float2(*(const __half2*)&v[j].z);
            float2 f3 = __half22float2(*(const __half2*)&v[j].w);
            a0 += f0.x; a1 += f0.y; a2 += f1.x; a3 += f1.y;
            a4 += f2.x; a5 += f2.y; a6 += f3.x; a7 += f3.y;
        }
    }
    float ri = rs_in[node];
    a0 *= ri; a1 *= ri; a2 *= ri; a3 *= ri;
    a4 *= ri; a5 *= ri; a6 *= ri; a7 *= ri;

    float4 o0 = bs4[2 * l];
    float4 o1 = bs4[2 * l + 1];
    int gbase = g << 3;
    #pragma unroll
    for (int m = 0; m < 8; m++) {
        float q0 = __shfl(a0, gbase + m, 64);
        float q1 = __shfl(a1, gbase + m, 64);
        float q2 = __shfl(a2, gbase + m, 64);
        float q3 = __shfl(a3, gbase + m, 64);
        float q4 = __shfl(a4, gbase + m, 64);
        float q5 = __shfl(a5, gbase + m, 64);
        float q6 = __shfl(a6, gbase + m, 64);
        float q7 = __shfl(a7, gbase + m, 64);
        int rb = (8 * m) * 16 + 2 * l;
        float4 w;
        w = Ws4[rb];            o0.x += q0*w.x; o0.y += q0*w.y; o0.z += q0*w.z; o0.w += q0*w.w;
        w = Ws4[rb + 1];        o1.x += q0*w.x; o1.y += q0*w.y; o1.z += q0*w.z; o1.w += q0*w.w;
        w = Ws4[rb + 16];       o0.x += q1*w.x; o0.y += q1*w.y; o0.z += q1*w.z; o0.w += q1*w.w;
        w = Ws4[rb + 17];       o1.x += q1*w.x; o1.y += q1*w.y; o1.z += q1*w.z; o1.w += q1*w.w;
        w = Ws4[rb + 32];       o0.x += q2*w.x; o0.y += q2*w.y; o0.z += q2*w.z; o0.w += q2*w.w;
        w = Ws4[rb + 33];       o1.x += q2*w.x; o1.y += q2*w.y; o1.z += q2*w.z; o1.w += q2*w.w;
        w = Ws4[rb + 48];       o0.x += q3*w.x; o0.y += q3*w.y; o0.z += q3*w.z; o0.w += q3*w.w;
        w = Ws4[rb + 49];       o1.x += q3*w.x; o1.y += q3*w.y; o1.z += q3*w.z; o1.w += q3*w.w;
        w = Ws4[rb + 64];       o0.x += q4*w.x; o0.y += q4*w.y; o0.z += q4*w.z; o0.w += q4*w.w;
        w = Ws4[rb + 65];       o1.x += q4*w.x; o1.y += q4*w.y; o1.z += q4*w.z; o1.w += q4*w.w;
        w = Ws4[rb + 80];       o0.x += q5*w.x; o0.y += q5*w.y; o0.z += q5*w.z; o0.w += q5*w.w;
        w = Ws4[rb + 81];       o1.x += q5*w.x; o1.y += q5*w.y; o1.z += q5*w.z; o1.w += q5*w.w;
        w = Ws4[rb + 96];       o0.x += q6*w.x; o0.y += q6*w.y; o0.z += q6*w.z; o0.w += q6*w.w;
        w = Ws4[rb + 97];       o1.x += q6*w.x; o1.y += q6*w.y; o1.z += q6*w.z; o1.w += q6*w.w;
        w = Ws4[rb + 112];      o0.x += q7*w.x; o0.y += q7*w.y; o0.z += q7*w.z; o0.w += q7*w.w;
        w = Ws4[rb + 113];      o1.x += q7*w.x; o1.y += q7*w.y; o1.z += q7*w.z; o1.w += q7*w.w;
    }
    if (SCALE_OUT) {
        float ro = rs_out[node];
        o0.x = (o0.x < 0.f ? 0.f : o0.x) * ro;
        o0.y = (o0.y < 0.f ? 0.f : o0.y) * ro;
        o0.z = (o0.z < 0.f ? 0.f : o0.z) * ro;
        o0.w = (o0.w < 0.f ? 0.f : o0.w) * ro;
        o1.x = (o1.x < 0.f ? 0.f : o1.x) * ro;
        o1.y = (o1.y < 0.f ? 0.f : o1.y) * ro;
        o1.z = (o1.z < 0.f ? 0.f : o1.z) * ro;
        o1.w = (o1.w < 0.f ? 0.f : o1.w) * ro;
        uint4 ho;
        *(__half2*)&ho.x = __float22half2_rn(make_float2(o0.x, o0.y));
        *(__half2*)&ho.y = __float22half2_rn(make_float2(o0.z, o0.w));
        *(__half2*)&ho.z = __float22half2_rn(make_float2(o1.x, o1.y));
        *(__half2*)&ho.w = __float22half2_rn(make_float2(o1.z, o1.w));
        ((uint4*)outp)[node * 8 + l] = ho;             // fp16 next-layer table
    } else {
        float4* o4 = (float4*)outp;
        o4[node * 16 + 2 * l]     = o0;                // fp32 final output
        o4[node * 16 + 2 * l + 1] = o1;
    }
}

extern "C" void kernel_launch(void* const* d_in, const int* in_sizes, int n_in,
                              void* d_out, int out_size, void* d_ws, size_t ws_size,
                              hipStream_t stream) {
    const float* x   = (const float*)d_in[0];
    const int*   ei  = (const int*)d_in[1];
    const int*   src = ei;
    const int*   dst = ei + N_EDGES;
    const float* W1 = (const float*)d_in[3];
    const float* b1 = (const float*)d_in[4];
    const float* W2 = (const float*)d_in[5];
    const float* b2 = (const float*)d_in[6];
    const float* W3 = (const float*)d_in[7];
    const float* b3 = (const float*)d_in[8];
    float* out = (float*)d_out;

    // workspace (~28 MB): identical layout to R14.
    char* ws = (char*)d_ws;
    float* rs        = (float*)ws;                                 // [2N]
    float* rs_out    = rs;
    float* rs_in     = rs + N_NODES;
    int*   row_start = (int*)(rs + 2 * N_NODES);                   // [N+256]
    int*   block_h   = row_start + (N_NODES + 256);                // [65536]
    int*   so        = block_h + 256 * CHUNKS;                     // [65536]
    unsigned short* csr_src = (unsigned short*)(so + 256 * CHUNKS);// [E+16]
    h4*    bufA      = (h4*)(csr_src + N_EDGES + 16);              // [(N+1)*16]
    h4*    bufB      = bufA + (size_t)(N_NODES + 1) * 16;          // [(N+1)*16]
    unsigned* partial = (unsigned*)(bufB + (size_t)(N_NODES + 1) * 16); // 8 MB
    int*   bpack     = (int*)bufB;                                 // 4 MB alias
    uint2* zeroA     = (uint2*)(bufA + (size_t)N_NODES * 16);      // row N_NODES
    uint2* zeroB     = (uint2*)(bufB + (size_t)N_NODES * 16);

    const int fb = N_NODES / 32;      // 2048 blocks (8 nodes/wave x 4 waves)

    edge_hist    <<<HB, 256, 0, stream>>>(src, dst, block_h, partial, zeroA, zeroB);
    part_scan    <<<1, 1024, 0, stream>>>(block_h, so);
    part_scatter <<<CHUNKS, 256, 0, stream>>>(src, dst, so, bpack);
    bucket_fused <<<256, 256, 0, stream>>>(bpack, so, row_start, rs_in, csr_src);
    oh2p_prescale<<<256, 256, 0, stream>>>(partial, rs_out, (const float4*)x, bufA);

    // layers: bufA -> bufB(fp16, scaled) -> bufA(fp16, scaled) -> d_out (fp32)
    fused_layer<true ><<<fb, 256, 0, stream>>>((const uint4*)bufA, row_start, csr_src, rs_out, rs_in, W1, b1, (void*)bufB);
    fused_layer<true ><<<fb, 256, 0, stream>>>((const uint4*)bufB, row_start, csr_src, rs_out, rs_in, W2, b2, (void*)bufA);
    fused_layer<false><<<fb, 256, 0, stream>>>((const uint4*)bufA, row_start, csr_src, rs_out, rs_in, W3, b3, (void*)out);
}